// Round 1
// baseline (2676.853 us; speedup 1.0000x reference)
//
#include <hip/hip_runtime.h>
#include <hip/hip_bf16.h>
#include <stdint.h>

#define CCH 128  // channels

// ---------------- CSR build ----------------

__global__ void hist_kernel(const int* __restrict__ rows, int* __restrict__ counts, int E) {
    int stride = gridDim.x * blockDim.x;
    for (int e = blockIdx.x * blockDim.x + threadIdx.x; e < E; e += stride)
        atomicAdd(&counts[rows[e]], 1);
}

// single-block Hillis-Steele scan over tiles of 1024; row_ptr[i+1] = inclusive sum
__global__ void scan_kernel(const int* __restrict__ counts, int* __restrict__ row_ptr, int n) {
    __shared__ int tile[1024];
    __shared__ int carry_s;
    int t = threadIdx.x;
    if (t == 0) { carry_s = 0; row_ptr[0] = 0; }
    __syncthreads();
    for (int base = 0; base < n; base += 1024) {
        int i = base + t;
        tile[t] = (i < n) ? counts[i] : 0;
        __syncthreads();
        for (int off = 1; off < 1024; off <<= 1) {
            int add = (t >= off) ? tile[t - off] : 0;
            __syncthreads();
            tile[t] += add;
            __syncthreads();
        }
        int carry = carry_s;
        int incl = tile[t];
        if (i < n) row_ptr[i + 1] = carry + incl;
        __syncthreads();
        if (t == 1023) carry_s = carry + incl;
        __syncthreads();
    }
}

__global__ void scatter_kernel(const int* __restrict__ rows, const int* __restrict__ cols,
                               const float* __restrict__ vals, const int* __restrict__ row_ptr,
                               int* __restrict__ fill, int2* __restrict__ edges, int E) {
    int stride = gridDim.x * blockDim.x;
    for (int e = blockIdx.x * blockDim.x + threadIdx.x; e < E; e += stride) {
        int r = rows[e];
        int pos = row_ptr[r] + atomicAdd(&fill[r], 1);
        edges[pos] = make_int2(cols[e], __float_as_int(vals[e]));
    }
}

// ---------------- GEMM: out = x @ W  (x:[N,128], W:[128,128]) ----------------

__global__ __launch_bounds__(256) void gemm_kernel(const float* __restrict__ x,
                                                   const float* __restrict__ w,
                                                   float* __restrict__ out, int n) {
    __shared__ float wl[CCH * CCH];
    for (int i = threadIdx.x; i < CCH * CCH / 4; i += blockDim.x)
        ((float4*)wl)[i] = ((const float4*)w)[i];
    __syncthreads();
    int lane = threadIdx.x & 63;
    int wid = (blockIdx.x * blockDim.x + threadIdx.x) >> 6;
    int nw = (gridDim.x * blockDim.x) >> 6;
    for (int row = wid; row < n; row += nw) {
        const float* xr = x + (size_t)row * CCH;
        float ax = 0.f, ay = 0.f;
#pragma unroll 4
        for (int k = 0; k < CCH; ++k) {
            float xv = xr[k];  // wave-uniform address -> broadcast load
            float2 wv = *(const float2*)(wl + k * CCH + 2 * lane);
            ax += xv * wv.x;
            ay += xv * wv.y;
        }
        ((float2*)(out + (size_t)row * CCH))[lane] = make_float2(ax, ay);
    }
}

// ---------------- SpMM: dst[row] = sum_e val_e * src[col_e]  (+identity on last) --------

__global__ __launch_bounds__(256) void spmm_kernel(const int* __restrict__ row_ptr,
                                                   const int2* __restrict__ edges,
                                                   const float* __restrict__ src,
                                                   float* __restrict__ dst,
                                                   const float* __restrict__ identity,
                                                   int n) {
    int lane = threadIdx.x & 63;
    int wid = (blockIdx.x * blockDim.x + threadIdx.x) >> 6;
    int nw = (gridDim.x * blockDim.x) >> 6;
    for (int row = wid; row < n; row += nw) {
        int start = row_ptr[row];
        int end = row_ptr[row + 1];
        float ax = 0.f, ay = 0.f;
        int e = start;
        int endu = start + ((end - start) & ~3);
        for (; e < endu; e += 4) {
            int2 e0 = edges[e];
            int2 e1 = edges[e + 1];
            int2 e2 = edges[e + 2];
            int2 e3 = edges[e + 3];
            float2 d0 = *(const float2*)(src + (size_t)e0.x * CCH + 2 * lane);
            float2 d1 = *(const float2*)(src + (size_t)e1.x * CCH + 2 * lane);
            float2 d2 = *(const float2*)(src + (size_t)e2.x * CCH + 2 * lane);
            float2 d3 = *(const float2*)(src + (size_t)e3.x * CCH + 2 * lane);
            float v0 = __int_as_float(e0.y), v1 = __int_as_float(e1.y);
            float v2 = __int_as_float(e2.y), v3 = __int_as_float(e3.y);
            ax += v0 * d0.x + v1 * d1.x + v2 * d2.x + v3 * d3.x;
            ay += v0 * d0.y + v1 * d1.y + v2 * d2.y + v3 * d3.y;
        }
        for (; e < end; ++e) {
            int2 ed = edges[e];
            float2 d = *(const float2*)(src + (size_t)ed.x * CCH + 2 * lane);
            float v = __int_as_float(ed.y);
            ax += v * d.x;
            ay += v * d.y;
        }
        if (identity) {
            float2 iv = *(const float2*)(identity + (size_t)row * CCH + 2 * lane);
            ax += iv.x;
            ay += iv.y;
        }
        *(float2*)(dst + (size_t)row * CCH + 2 * lane) = make_float2(ax, ay);
    }
}

// ---------------- launch ----------------

static inline size_t align256(size_t x) { return (x + 255) & ~(size_t)255; }

extern "C" void kernel_launch(void* const* d_in, const int* in_sizes, int n_in,
                              void* d_out, int out_size, void* d_ws, size_t ws_size,
                              hipStream_t stream) {
    const float* x = (const float*)d_in[0];
    const float* w = (const float*)d_in[1];
    const float* lap_vals = (const float*)d_in[2];
    const int* lap_rows = (const int*)d_in[3];
    const int* lap_cols = (const int*)d_in[4];

    const int N = in_sizes[0] / CCH;   // 100000
    const int E = in_sizes[2];         // 3200000

    // workspace layout
    char* ws = (char*)d_ws;
    size_t off = 0;
    float* bufA = (float*)(ws + off);  off = align256(off + (size_t)N * CCH * sizeof(float));
    int2* edges = (int2*)(ws + off);   off = align256(off + (size_t)E * sizeof(int2));
    int* row_ptr = (int*)(ws + off);   off = align256(off + (size_t)(N + 1) * sizeof(int));
    int* counts = (int*)(ws + off);    off = align256(off + (size_t)N * sizeof(int));
    int* fill = (int*)(ws + off);      off = align256(off + (size_t)N * sizeof(int));
    (void)ws_size;

    float* out = (float*)d_out;

    // zero counts + fill (adjacent would need 2 calls due to alignment padding; do both)
    hipMemsetAsync(counts, 0, (size_t)N * sizeof(int), stream);
    hipMemsetAsync(fill, 0, (size_t)N * sizeof(int), stream);

    // CSR build
    hist_kernel<<<2048, 256, 0, stream>>>(lap_rows, counts, E);
    scan_kernel<<<1, 1024, 0, stream>>>(counts, row_ptr, N);
    scatter_kernel<<<2048, 256, 0, stream>>>(lap_rows, lap_cols, lap_vals, row_ptr, fill, edges, E);

    // GEMM -> d_out (so that after 8 ping-pong steps the result lands back in d_out)
    gemm_kernel<<<512, 256, 0, stream>>>(x, w, out, N);

    // 8 propagation steps: out -> bufA -> out -> ... -> out (step 8 into d_out, +identity)
    int spmm_blocks = (N + 3) / 4;  // 4 waves (rows) per 256-thread block
    const float* src = out;
    float* dst = bufA;
    for (int step = 0; step < 8; ++step) {
        const float* ident = (step == 7) ? x : nullptr;
        spmm_kernel<<<spmm_blocks, 256, 0, stream>>>(row_ptr, edges, src, dst, ident, N);
        const float* t = dst;
        dst = (float*)src;
        src = t;
    }
    // after 8 swaps, final write was into d_out (even number of swaps from out)
}

// Round 2
// 2644.770 us; speedup vs baseline: 1.0121x; 1.0121x over previous
//
#include <hip/hip_runtime.h>
#include <hip/hip_bf16.h>
#include <stdint.h>

#define CCH 128  // channels

// ---------------- CSR build ----------------

__global__ void hist_kernel(const int* __restrict__ rows, int* __restrict__ counts, int E) {
    int stride = gridDim.x * blockDim.x;
    for (int e = blockIdx.x * blockDim.x + threadIdx.x; e < E; e += stride)
        atomicAdd(&counts[rows[e]], 1);
}

// single-block Hillis-Steele scan over tiles of 1024; row_ptr[i+1] = inclusive sum
__global__ void scan_kernel(const int* __restrict__ counts, int* __restrict__ row_ptr, int n) {
    __shared__ int tile[1024];
    __shared__ int carry_s;
    int t = threadIdx.x;
    if (t == 0) { carry_s = 0; row_ptr[0] = 0; }
    __syncthreads();
    for (int base = 0; base < n; base += 1024) {
        int i = base + t;
        tile[t] = (i < n) ? counts[i] : 0;
        __syncthreads();
        for (int off = 1; off < 1024; off <<= 1) {
            int add = (t >= off) ? tile[t - off] : 0;
            __syncthreads();
            tile[t] += add;
            __syncthreads();
        }
        int carry = carry_s;
        int incl = tile[t];
        if (i < n) row_ptr[i + 1] = carry + incl;
        __syncthreads();
        if (t == 1023) carry_s = carry + incl;
        __syncthreads();
    }
}

__global__ void scatter_kernel(const int* __restrict__ rows, const int* __restrict__ cols,
                               const float* __restrict__ vals, const int* __restrict__ row_ptr,
                               int* __restrict__ fill, int2* __restrict__ edges, int E) {
    int stride = gridDim.x * blockDim.x;
    for (int e = blockIdx.x * blockDim.x + threadIdx.x; e < E; e += stride) {
        int r = rows[e];
        int pos = row_ptr[r] + atomicAdd(&fill[r], 1);
        edges[pos] = make_int2(cols[e], __float_as_int(vals[e]));
    }
}

// ---------------- GEMM: out = x @ W  (x:[N,128], W:[128,128]) ----------------
// Block = 256 threads covers 64 rows x 128 cols. Thread (tr=tid>>5, tc=tid&31)
// computes an 8-row x 4-col micro-tile: rows blk*64 + tr*8 .. +7, cols tc*4..+3.
// W staged in LDS (64 KB); x read as float4 broadcast loads (L1-resident,
// 32 KB of x per block). Per 4-k chunk: 8 global b128 + 4 ds_read_b128 + 128 FMA
// -> VALU-bound.

#define GEMM_ROWS 64

__global__ __launch_bounds__(256) void gemm_kernel(const float* __restrict__ x,
                                                   const float* __restrict__ w,
                                                   float* __restrict__ out, int n) {
    __shared__ float wl[CCH * CCH];
    for (int i = threadIdx.x; i < CCH * CCH / 4; i += 256)
        ((float4*)wl)[i] = ((const float4*)w)[i];
    __syncthreads();

    int tc = threadIdx.x & 31;   // col group: cols tc*4 .. tc*4+3
    int tr = threadIdx.x >> 5;   // row group 0..7
    int rbase = blockIdx.x * GEMM_ROWS + tr * 8;
    int nr = n - rbase;
    if (nr > 8) nr = 8;
    if (nr <= 0) nr = 0;

    float acc[8][4] = {};
    const float* xp = x + (size_t)rbase * CCH;

    for (int k = 0; k < CCH; k += 4) {
        float4 xv[8];
#pragma unroll
        for (int j = 0; j < 8; ++j)
            xv[j] = (j < nr) ? *(const float4*)(xp + (size_t)j * CCH + k)
                             : make_float4(0.f, 0.f, 0.f, 0.f);
#pragma unroll
        for (int kk = 0; kk < 4; ++kk) {
            float4 wv = *(const float4*)(wl + (k + kk) * CCH + tc * 4);
#pragma unroll
            for (int j = 0; j < 8; ++j) {
                float xs = (kk == 0) ? xv[j].x : (kk == 1) ? xv[j].y : (kk == 2) ? xv[j].z : xv[j].w;
                acc[j][0] += xs * wv.x;
                acc[j][1] += xs * wv.y;
                acc[j][2] += xs * wv.z;
                acc[j][3] += xs * wv.w;
            }
        }
    }
#pragma unroll
    for (int j = 0; j < 8; ++j)
        if (j < nr)
            *(float4*)(out + (size_t)(rbase + j) * CCH + tc * 4) = *(float4*)acc[j];
}

// ---------------- SpMM: dst[row] = sum_e val_e * src[col_e]  (+identity on last) --------
// Two rows per wave, lockstep masked unroll-4 chunks -> up to 8 outstanding
// gathers per wave, no scalar tail (OOB edges get val=0, col=edges[0].x).

__global__ __launch_bounds__(256) void spmm_kernel(const int* __restrict__ row_ptr,
                                                   const int2* __restrict__ edges,
                                                   const float* __restrict__ src,
                                                   float* __restrict__ dst,
                                                   const float* __restrict__ identity,
                                                   int n) {
    int lane = threadIdx.x & 63;
    int wid = (blockIdx.x * blockDim.x + threadIdx.x) >> 6;
    int r0 = wid * 2;
    if (r0 >= n) return;
    int r1 = r0 + 1;
    bool has1 = (r1 < n);

    int s0 = row_ptr[r0], e0 = row_ptr[r0 + 1];
    int s1 = has1 ? row_ptr[r1] : 0;
    int e1 = has1 ? row_ptr[r1 + 1] : 0;
    int c0 = (e0 - s0 + 3) >> 2;
    int c1 = (e1 - s1 + 3) >> 2;
    int chunks = c0 > c1 ? c0 : c1;

    int off = 2 * lane;
    float a0x = 0.f, a0y = 0.f, a1x = 0.f, a1y = 0.f;

    for (int it = 0; it < chunks; ++it) {
        int b0 = s0 + it * 4;
        int b1 = s1 + it * 4;
        int2 ed0[4], ed1[4];
#pragma unroll
        for (int t = 0; t < 4; ++t) {
            int i0 = b0 + t;
            bool ok0 = i0 < e0;
            ed0[t] = edges[ok0 ? i0 : 0];
            if (!ok0) ed0[t].y = 0;  // val = 0.0f
            int i1 = b1 + t;
            bool ok1 = i1 < e1;
            ed1[t] = edges[ok1 ? i1 : 0];
            if (!ok1) ed1[t].y = 0;
        }
        float2 g0[4], g1[4];
#pragma unroll
        for (int t = 0; t < 4; ++t)
            g0[t] = *(const float2*)(src + (size_t)ed0[t].x * CCH + off);
#pragma unroll
        for (int t = 0; t < 4; ++t)
            g1[t] = *(const float2*)(src + (size_t)ed1[t].x * CCH + off);
#pragma unroll
        for (int t = 0; t < 4; ++t) {
            float v0 = __int_as_float(ed0[t].y);
            a0x += v0 * g0[t].x;
            a0y += v0 * g0[t].y;
            float v1 = __int_as_float(ed1[t].y);
            a1x += v1 * g1[t].x;
            a1y += v1 * g1[t].y;
        }
    }

    if (identity) {
        float2 iv0 = *(const float2*)(identity + (size_t)r0 * CCH + off);
        a0x += iv0.x;
        a0y += iv0.y;
        if (has1) {
            float2 iv1 = *(const float2*)(identity + (size_t)r1 * CCH + off);
            a1x += iv1.x;
            a1y += iv1.y;
        }
    }
    *(float2*)(dst + (size_t)r0 * CCH + off) = make_float2(a0x, a0y);
    if (has1)
        *(float2*)(dst + (size_t)r1 * CCH + off) = make_float2(a1x, a1y);
}

// ---------------- launch ----------------

static inline size_t align256(size_t x) { return (x + 255) & ~(size_t)255; }

extern "C" void kernel_launch(void* const* d_in, const int* in_sizes, int n_in,
                              void* d_out, int out_size, void* d_ws, size_t ws_size,
                              hipStream_t stream) {
    const float* x = (const float*)d_in[0];
    const float* w = (const float*)d_in[1];
    const float* lap_vals = (const float*)d_in[2];
    const int* lap_rows = (const int*)d_in[3];
    const int* lap_cols = (const int*)d_in[4];

    const int N = in_sizes[0] / CCH;   // 100000
    const int E = in_sizes[2];         // 3200000

    // workspace layout
    char* ws = (char*)d_ws;
    size_t off = 0;
    float* bufA = (float*)(ws + off);  off = align256(off + (size_t)N * CCH * sizeof(float));
    int2* edges = (int2*)(ws + off);   off = align256(off + (size_t)E * sizeof(int2));
    int* row_ptr = (int*)(ws + off);   off = align256(off + (size_t)(N + 1) * sizeof(int));
    int* counts = (int*)(ws + off);    off = align256(off + (size_t)N * sizeof(int));
    int* fill = (int*)(ws + off);      off = align256(off + (size_t)N * sizeof(int));
    (void)ws_size;

    float* out = (float*)d_out;

    hipMemsetAsync(counts, 0, (size_t)N * sizeof(int), stream);
    hipMemsetAsync(fill, 0, (size_t)N * sizeof(int), stream);

    // CSR build
    hist_kernel<<<2048, 256, 0, stream>>>(lap_rows, counts, E);
    scan_kernel<<<1, 1024, 0, stream>>>(counts, row_ptr, N);
    scatter_kernel<<<2048, 256, 0, stream>>>(lap_rows, lap_cols, lap_vals, row_ptr, fill, edges, E);

    // GEMM -> d_out (so that after 8 ping-pong steps the result lands back in d_out)
    gemm_kernel<<<(N + GEMM_ROWS - 1) / GEMM_ROWS, 256, 0, stream>>>(x, w, out, N);

    // 8 propagation steps: out -> bufA -> out -> ... -> out (step 8 into d_out, +identity)
    int waves_needed = (N + 1) / 2;                 // 2 rows per wave
    int spmm_blocks = (waves_needed + 3) / 4;       // 4 waves per 256-thread block
    const float* src = out;
    float* dst = bufA;
    for (int step = 0; step < 8; ++step) {
        const float* ident = (step == 7) ? x : nullptr;
        spmm_kernel<<<spmm_blocks, 256, 0, stream>>>(row_ptr, edges, src, dst, ident, N);
        const float* t = dst;
        dst = (float*)src;
        src = t;
    }
}

// Round 3
// 1728.166 us; speedup vs baseline: 1.5490x; 1.5304x over previous
//
#include <hip/hip_runtime.h>
#include <hip/hip_bf16.h>
#include <hip/hip_fp16.h>
#include <stdint.h>

#define CCH 128  // channels
#define FINAL_SCALE 268435456.0f  // 16^7: undo 7 steps of 1/16 scaling (step 8 unscaled)

// ---------------- CSR build ----------------

__global__ void hist_kernel(const int* __restrict__ rows, int* __restrict__ counts, int E) {
    int stride = gridDim.x * blockDim.x;
    for (int e = blockIdx.x * blockDim.x + threadIdx.x; e < E; e += stride)
        atomicAdd(&counts[rows[e]], 1);
}

// Phase A: per-block (1024) inclusive scan -> row_ptr[i+1] (tile-local), block sum -> partials
__global__ __launch_bounds__(1024) void scanA_kernel(const int* __restrict__ counts,
                                                     int* __restrict__ row_ptr,
                                                     int* __restrict__ partials, int n) {
    __shared__ int tile[1024];
    int t = threadIdx.x;
    int i = blockIdx.x * 1024 + t;
    tile[t] = (i < n) ? counts[i] : 0;
    __syncthreads();
    for (int off = 1; off < 1024; off <<= 1) {
        int add = (t >= off) ? tile[t - off] : 0;
        __syncthreads();
        tile[t] += add;
        __syncthreads();
    }
    if (i < n) row_ptr[i + 1] = tile[t];
    if (t == 1023) partials[blockIdx.x] = tile[1023];
}

// Phase B: single block scans partials (nb <= 1024) in place -> exclusive offsets
__global__ __launch_bounds__(1024) void scanB_kernel(int* __restrict__ partials,
                                                     int* __restrict__ row_ptr, int nb) {
    __shared__ int tile[1024];
    int t = threadIdx.x;
    tile[t] = (t < nb) ? partials[t] : 0;
    __syncthreads();
    for (int off = 1; off < 1024; off <<= 1) {
        int add = (t >= off) ? tile[t - off] : 0;
        __syncthreads();
        tile[t] += add;
        __syncthreads();
    }
    if (t < nb) partials[t] = (t == 0) ? 0 : tile[t - 1];
    if (t == 0) row_ptr[0] = 0;
}

// Phase C: add block offsets
__global__ void scanC_kernel(const int* __restrict__ partials, int* __restrict__ row_ptr, int n) {
    int i = blockIdx.x * blockDim.x + threadIdx.x;
    if (i < n) row_ptr[i + 1] += partials[i >> 10];
}

__global__ void scatter_kernel(const int* __restrict__ rows, const int* __restrict__ cols,
                               const float* __restrict__ vals, const int* __restrict__ row_ptr,
                               int* __restrict__ fill, int2* __restrict__ edges, int E) {
    int stride = gridDim.x * blockDim.x;
    for (int e = blockIdx.x * blockDim.x + threadIdx.x; e < E; e += stride) {
        int r = rows[e];
        int pos = row_ptr[r] + atomicAdd(&fill[r], 1);
        edges[pos] = make_int2(cols[e], __float_as_int(vals[e]));
    }
}

// ---------------- GEMM: t0 = x @ W, stored fp16  (x:[N,128], W:[128,128]) ----------------

#define GEMM_ROWS 64

__global__ __launch_bounds__(256) void gemm_kernel(const float* __restrict__ x,
                                                   const float* __restrict__ w,
                                                   __half* __restrict__ out, int n) {
    __shared__ float wl[CCH * CCH];
    for (int i = threadIdx.x; i < CCH * CCH / 4; i += 256)
        ((float4*)wl)[i] = ((const float4*)w)[i];
    __syncthreads();

    int tc = threadIdx.x & 31;   // col group: cols tc*4 .. tc*4+3
    int tr = threadIdx.x >> 5;   // row group 0..7
    int rbase = blockIdx.x * GEMM_ROWS + tr * 8;
    int nr = n - rbase;
    if (nr > 8) nr = 8;
    if (nr <= 0) nr = 0;

    float acc[8][4] = {};
    const float* xp = x + (size_t)rbase * CCH;

    for (int k = 0; k < CCH; k += 4) {
        float4 xv[8];
#pragma unroll
        for (int j = 0; j < 8; ++j)
            xv[j] = (j < nr) ? *(const float4*)(xp + (size_t)j * CCH + k)
                             : make_float4(0.f, 0.f, 0.f, 0.f);
#pragma unroll
        for (int kk = 0; kk < 4; ++kk) {
            float4 wv = *(const float4*)(wl + (k + kk) * CCH + tc * 4);
#pragma unroll
            for (int j = 0; j < 8; ++j) {
                float xs = (kk == 0) ? xv[j].x : (kk == 1) ? xv[j].y : (kk == 2) ? xv[j].z : xv[j].w;
                acc[j][0] += xs * wv.x;
                acc[j][1] += xs * wv.y;
                acc[j][2] += xs * wv.z;
                acc[j][3] += xs * wv.w;
            }
        }
    }
#pragma unroll
    for (int j = 0; j < 8; ++j)
        if (j < nr) {
            __half2* orow = (__half2*)(out + (size_t)(rbase + j) * CCH + tc * 4);
            orow[0] = __float22half2_rn(make_float2(acc[j][0], acc[j][1]));
            orow[1] = __float22half2_rn(make_float2(acc[j][2], acc[j][3]));
        }
}

// ---------------- SpMM (fp16 src): dst[row] = (1/16) * sum_e val_e * src[col_e] ----------
// FINAL=1: dst = identity + FINAL_SCALE * sum (fp32, to d_out)
// Two rows per wave, lockstep masked unroll-4 -> 8 outstanding gathers per wave.

template <int FINAL>
__global__ __launch_bounds__(256) void spmm_kernel(const int* __restrict__ row_ptr,
                                                   const int2* __restrict__ edges,
                                                   const __half2* __restrict__ src,
                                                   __half2* __restrict__ dsth,
                                                   float* __restrict__ dstf,
                                                   const float* __restrict__ identity,
                                                   int n) {
    int lane = threadIdx.x & 63;
    int wid = (blockIdx.x * blockDim.x + threadIdx.x) >> 6;
    int r0 = wid * 2;
    if (r0 >= n) return;
    int r1 = r0 + 1;
    bool has1 = (r1 < n);

    int s0 = row_ptr[r0], e0 = row_ptr[r0 + 1];
    int s1 = has1 ? row_ptr[r1] : 0;
    int e1 = has1 ? row_ptr[r1 + 1] : 0;
    int c0 = (e0 - s0 + 3) >> 2;
    int c1 = (e1 - s1 + 3) >> 2;
    int chunks = c0 > c1 ? c0 : c1;

    float a0x = 0.f, a0y = 0.f, a1x = 0.f, a1y = 0.f;

    for (int it = 0; it < chunks; ++it) {
        int b0 = s0 + it * 4;
        int b1 = s1 + it * 4;
        int2 ed0[4], ed1[4];
#pragma unroll
        for (int t = 0; t < 4; ++t) {
            int i0 = b0 + t;
            bool ok0 = i0 < e0;
            ed0[t] = edges[ok0 ? i0 : 0];
            if (!ok0) ed0[t].y = 0;  // val = 0.0f
            int i1 = b1 + t;
            bool ok1 = i1 < e1;
            ed1[t] = edges[ok1 ? i1 : 0];
            if (!ok1) ed1[t].y = 0;
        }
        __half2 g0[4], g1[4];
#pragma unroll
        for (int t = 0; t < 4; ++t)
            g0[t] = src[(size_t)ed0[t].x * 64 + lane];
#pragma unroll
        for (int t = 0; t < 4; ++t)
            g1[t] = src[(size_t)ed1[t].x * 64 + lane];
#pragma unroll
        for (int t = 0; t < 4; ++t) {
            float v0 = __int_as_float(ed0[t].y);
            float2 f0 = __half22float2(g0[t]);
            a0x += v0 * f0.x;
            a0y += v0 * f0.y;
            float v1 = __int_as_float(ed1[t].y);
            float2 f1 = __half22float2(g1[t]);
            a1x += v1 * f1.x;
            a1y += v1 * f1.y;
        }
    }

    if (FINAL) {
        float2 iv0 = *(const float2*)(identity + (size_t)r0 * CCH + 2 * lane);
        *(float2*)(dstf + (size_t)r0 * CCH + 2 * lane) =
            make_float2(iv0.x + a0x * FINAL_SCALE, iv0.y + a0y * FINAL_SCALE);
        if (has1) {
            float2 iv1 = *(const float2*)(identity + (size_t)r1 * CCH + 2 * lane);
            *(float2*)(dstf + (size_t)r1 * CCH + 2 * lane) =
                make_float2(iv1.x + a1x * FINAL_SCALE, iv1.y + a1y * FINAL_SCALE);
        }
    } else {
        dsth[(size_t)r0 * 64 + lane] = __float22half2_rn(make_float2(a0x * 0.0625f, a0y * 0.0625f));
        if (has1)
            dsth[(size_t)r1 * 64 + lane] = __float22half2_rn(make_float2(a1x * 0.0625f, a1y * 0.0625f));
    }
}

// ---------------- launch ----------------

static inline size_t align256(size_t x) { return (x + 255) & ~(size_t)255; }

extern "C" void kernel_launch(void* const* d_in, const int* in_sizes, int n_in,
                              void* d_out, int out_size, void* d_ws, size_t ws_size,
                              hipStream_t stream) {
    const float* x = (const float*)d_in[0];
    const float* w = (const float*)d_in[1];
    const float* lap_vals = (const float*)d_in[2];
    const int* lap_rows = (const int*)d_in[3];
    const int* lap_cols = (const int*)d_in[4];

    const int N = in_sizes[0] / CCH;   // 100000
    const int E = in_sizes[2];         // 3200000
    const int NB = (N + 1023) / 1024;  // scan blocks

    // workspace layout
    char* ws = (char*)d_ws;
    size_t off = 0;
    __half* bufA = (__half*)(ws + off); off = align256(off + (size_t)N * CCH * sizeof(__half));
    __half* bufB = (__half*)(ws + off); off = align256(off + (size_t)N * CCH * sizeof(__half));
    int2* edges = (int2*)(ws + off);    off = align256(off + (size_t)E * sizeof(int2));
    int* row_ptr = (int*)(ws + off);    off = align256(off + (size_t)(N + 1) * sizeof(int));
    int* counts = (int*)(ws + off);     off = align256(off + (size_t)N * sizeof(int));
    int* fill = (int*)(ws + off);       off = align256(off + (size_t)N * sizeof(int));
    int* partials = (int*)(ws + off);   off = align256(off + (size_t)NB * sizeof(int));
    (void)ws_size;

    float* out = (float*)d_out;

    hipMemsetAsync(counts, 0, (size_t)N * sizeof(int), stream);
    hipMemsetAsync(fill, 0, (size_t)N * sizeof(int), stream);

    // CSR build
    hist_kernel<<<2048, 256, 0, stream>>>(lap_rows, counts, E);
    scanA_kernel<<<NB, 1024, 0, stream>>>(counts, row_ptr, partials, N);
    scanB_kernel<<<1, 1024, 0, stream>>>(partials, row_ptr, NB);
    scanC_kernel<<<(N + 255) / 256, 256, 0, stream>>>(partials, row_ptr, N);
    scatter_kernel<<<2048, 256, 0, stream>>>(lap_rows, lap_cols, lap_vals, row_ptr, fill, edges, E);

    // GEMM -> bufA (fp16 t0)
    gemm_kernel<<<(N + GEMM_ROWS - 1) / GEMM_ROWS, 256, 0, stream>>>(x, w, bufA, N);

    // steps 1..7 fp16 ping-pong (each scaled 1/16), step 8 fp32 -> d_out (+identity, x16^7)
    int waves_needed = (N + 1) / 2;            // 2 rows per wave
    int spmm_blocks = (waves_needed + 3) / 4;  // 4 waves per 256-thread block
    const __half2* src = (const __half2*)bufA;
    __half2* dst = (__half2*)bufB;
    for (int step = 1; step <= 7; ++step) {
        spmm_kernel<0><<<spmm_blocks, 256, 0, stream>>>(row_ptr, edges, src, dst, nullptr, nullptr, N);
        __half2* t = (__half2*)src;
        src = (const __half2*)dst;
        dst = t;
    }
    // after 7 steps t7 is in bufB (src points at it)
    spmm_kernel<1><<<spmm_blocks, 256, 0, stream>>>(row_ptr, edges, src, nullptr, out, x, N);
}